// Round 3
// baseline (69.655 us; speedup 1.0000x reference)
//
#include <hip/hip_runtime.h>
#include <hip/hip_bf16.h>

#define T_LEN 2400
#define LPC_N 16
#define FRAME 160
#define BLOCK 256
#define GROUPS_PER_ROW (T_LEN / 4)   // 600 groups of 4 outputs per batch row

// sig: (B, 2400, 1) f32 in [0,255); lpc: (B, 15, 16) f32; out: (B, 2400, 1) f32
// One thread = 4 consecutive outputs (aligned). No LDS, no barrier: the 20
// inputs each thread needs are 5 aligned float4 loads (5x overlap across
// threads is L1-served); mu-law decode is redone per thread in registers
// (exp2 is 1/4-rate VALU -- the redundancy costs <1us chip-wide).
__global__ __launch_bounds__(BLOCK)
void diff_pred_26319559589961_kernel(const float* __restrict__ sig,
                                     const float* __restrict__ lpc,
                                     float* __restrict__ out)
{
    const int g = blockIdx.x * BLOCK + threadIdx.x;     // global group id
    const int b = g / GROUPS_PER_ROW;
    const int t = (g - b * GROUPS_PER_ROW) * 4;         // group start sample

    // ---- load + decode 20 samples [t-16, t+4) into registers ----
    // u2l(v) = copysign((32768/255) * (2^(|v-128|/16) - 1), v-128)
    // pad (t_in < 0) fed v=128 -> decodes to exactly 0
    const float* sp = sig + (size_t)b * T_LEN + (t - LPC_N);
    float r[20];
    #pragma unroll
    for (int j = 0; j < 5; ++j) {
        const int start = t - LPC_N + 4 * j;            // multiple of 4
        float4 v = make_float4(128.0f, 128.0f, 128.0f, 128.0f);
        if (start >= 0)
            v = *(const float4*)(sp + 4 * j);           // global_load_dwordx4
        const float ux = v.x - 128.0f, uy = v.y - 128.0f,
                    uz = v.z - 128.0f, uw = v.w - 128.0f;
        r[4*j + 0] = copysignf((32768.0f/255.0f) * (exp2f(fabsf(ux) * 0.0625f) - 1.0f), ux);
        r[4*j + 1] = copysignf((32768.0f/255.0f) * (exp2f(fabsf(uy) * 0.0625f) - 1.0f), uy);
        r[4*j + 2] = copysignf((32768.0f/255.0f) * (exp2f(fabsf(uz) * 0.0625f) - 1.0f), uz);
        r[4*j + 3] = copysignf((32768.0f/255.0f) * (exp2f(fabsf(uw) * 0.0625f) - 1.0f), uw);
    }

    // ---- per-frame coefficients (160 % 4 == 0 -> one frame per group) ----
    const int frame = t / FRAME;
    const float4* c = (const float4*)(lpc + ((size_t)b * 15 + frame) * LPC_N);
    const float4 c0 = c[0], c1 = c[1], c2 = c[2], c3 = c[3];
    const float cf[16] = { c0.x, c0.y, c0.z, c0.w,
                           c1.x, c1.y, c1.z, c1.w,
                           c2.x, c2.y, c2.z, c2.w,
                           c3.x, c3.y, c3.z, c3.w };

    // ---- 16-tap prediction + l2u re-encode, 4 outputs ----
    float4 o;
    float* op = &o.x;
    #pragma unroll
    for (int k = 0; k < 4; ++k) {
        float acc = 0.0f;
        #pragma unroll
        for (int i = 0; i < LPC_N; ++i)
            acc += cf[i] * r[16 + k - i];
        const float pred = -acc;
        // l2u(p) = clip(128 + copysign(16*log2(1 + (255/32768)|p|), p), 0, 255)
        const float u = copysignf(
            16.0f * __log2f(1.0f + (255.0f/32768.0f) * fabsf(pred)), pred);
        op[k] = fminf(fmaxf(128.0f + u, 0.0f), 255.0f);
    }
    *(float4*)(out + (size_t)b * T_LEN + t) = o;        // global_store_dwordx4
}

extern "C" void kernel_launch(void* const* d_in, const int* in_sizes, int n_in,
                              void* d_out, int out_size, void* d_ws, size_t ws_size,
                              hipStream_t stream) {
    const float* sig = (const float*)d_in[0];   // (B, 2400, 1)
    const float* lpc = (const float*)d_in[1];   // (B, 15, 16)
    float* out = (float*)d_out;                 // (B, 2400, 1)

    const int B = in_sizes[0] / T_LEN;
    const int total_groups = B * GROUPS_PER_ROW;        // 614400 for B=1024
    diff_pred_26319559589961_kernel<<<total_groups / BLOCK, BLOCK, 0, stream>>>(sig, lpc, out);
}

// Round 4
// 65.373 us; speedup vs baseline: 1.0655x; 1.0655x over previous
//
#include <hip/hip_runtime.h>
#include <hip/hip_bf16.h>

#define T_LEN 2400
#define LPC_N 16
#define FRAME 160
#define BLOCK 640                    // 10 waves; one block per batch row
#define NDEC  ((T_LEN + LPC_N) / 4)  // 604 decode groups (float4) incl. 16-sample history
#define NOUT  (T_LEN / 4)            // 600 output groups

// sig: (B, 2400, 1) f32 in [0,255); lpc: (B, 15, 16) f32; out: (B, 2400, 1) f32
// One block per row. Phase 1: decode row once into LDS (604 lanes x float4).
// Phase 2: 600 lanes x 4 outputs, 5 aligned ds_read_b128 each. Single barrier.
__global__ __launch_bounds__(BLOCK)
void diff_pred_26319559589961_kernel(const float* __restrict__ sig,
                                     const float* __restrict__ lpc,
                                     float* __restrict__ out)
{
    __shared__ float xs[T_LEN + LPC_N];   // xs[16 + t] = decoded sample t; xs[0..15] = 0

    const int b   = blockIdx.x;
    const int tid = threadIdx.x;

    // ---- phase 1: mu-law decode, one float4 per lane ----
    // u2l(v) = copysign((32768/255) * (2^(|v-128|/16) - 1), v-128)
    if (tid < NDEC) {
        const int start = 4 * tid - LPC_N;            // -16,-12,-8,-4, 0, 4, ...
        float4 r = make_float4(0.0f, 0.0f, 0.0f, 0.0f);
        if (start >= 0) {                             // tid >= 4: real samples
            const float4 v = *(const float4*)(sig + (size_t)b * T_LEN + start);
            const float ux = v.x - 128.0f, uy = v.y - 128.0f,
                        uz = v.z - 128.0f, uw = v.w - 128.0f;
            r.x = copysignf((32768.0f/255.0f) * (exp2f(fabsf(ux) * 0.0625f) - 1.0f), ux);
            r.y = copysignf((32768.0f/255.0f) * (exp2f(fabsf(uy) * 0.0625f) - 1.0f), uy);
            r.z = copysignf((32768.0f/255.0f) * (exp2f(fabsf(uz) * 0.0625f) - 1.0f), uz);
            r.w = copysignf((32768.0f/255.0f) * (exp2f(fabsf(uw) * 0.0625f) - 1.0f), uw);
        }
        *(float4*)(xs + 4 * tid) = r;                 // ds_write_b128, aligned
    }
    __syncthreads();

    // ---- phase 2: 4 outputs per lane ----
    if (tid < NOUT) {
        const int t     = 4 * tid;                    // 160 % 4 == 0 -> one frame/group
        const int frame = tid / 40;                   // t / FRAME
        const float4* c = (const float4*)(lpc + ((size_t)b * 15 + frame) * LPC_N);
        const float4 c0 = c[0], c1 = c[1], c2 = c[2], c3 = c[3];
        const float cf[16] = { c0.x, c0.y, c0.z, c0.w,
                               c1.x, c1.y, c1.z, c1.w,
                               c2.x, c2.y, c2.z, c2.w,
                               c3.x, c3.y, c3.z, c3.w };

        // r[m] = xt[t - 16 + m], m = 0..19  (5 aligned ds_read_b128)
        float r[20];
        *(float4*)(r +  0) = *(const float4*)(xs + t +  0);
        *(float4*)(r +  4) = *(const float4*)(xs + t +  4);
        *(float4*)(r +  8) = *(const float4*)(xs + t +  8);
        *(float4*)(r + 12) = *(const float4*)(xs + t + 12);
        *(float4*)(r + 16) = *(const float4*)(xs + t + 16);

        float4 o;
        float* op = &o.x;
        #pragma unroll
        for (int k = 0; k < 4; ++k) {
            float acc = 0.0f;
            #pragma unroll
            for (int i = 0; i < LPC_N; ++i)
                acc += cf[i] * r[16 + k - i];
            const float pred = -acc;
            // l2u(p) = clip(128 + copysign(16*log2(1 + (255/32768)|p|), p), 0, 255)
            const float u = copysignf(
                16.0f * __log2f(1.0f + (255.0f/32768.0f) * fabsf(pred)), pred);
            op[k] = fminf(fmaxf(128.0f + u, 0.0f), 255.0f);
        }
        *(float4*)(out + (size_t)b * T_LEN + t) = o;  // global_store_dwordx4
    }
}

extern "C" void kernel_launch(void* const* d_in, const int* in_sizes, int n_in,
                              void* d_out, int out_size, void* d_ws, size_t ws_size,
                              hipStream_t stream) {
    const float* sig = (const float*)d_in[0];   // (B, 2400, 1)
    const float* lpc = (const float*)d_in[1];   // (B, 15, 16)
    float* out = (float*)d_out;                 // (B, 2400, 1)

    const int B = in_sizes[0] / T_LEN;          // 1024
    diff_pred_26319559589961_kernel<<<B, BLOCK, 0, stream>>>(sig, lpc, out);
}